// Round 2
// baseline (1466.487 us; speedup 1.0000x reference)
//
#include <hip/hip_runtime.h>
#include <math.h>

#define NJ 17
#define DD 128
#define XS 132      // fp32 row stride for sX/sX0/sV
#define LBS 264     // ushort row stride for sLb/sRb (256 + 8 pad)
#define XBS 136     // ushort row stride for sXh/sXl (128 + 8 pad)
#define SS 20       // score row stride
#define TOKE (NJ*DD)

typedef unsigned short ushort_t;
typedef unsigned int uint_t;
typedef __attribute__((ext_vector_type(8))) short short8;
typedef __attribute__((ext_vector_type(4))) float f32x4;

// adjacency bitmasks (both dirs + diag)
__device__ __constant__ unsigned int ADJM[NJ] = {
    0x93u, 0x7u, 0xEu, 0xCu, 0x31u, 0x70u, 0x60u,
    0x181u, 0x4B80u, 0x700u, 0x600u, 0x1900u, 0x3800u, 0x3000u,
    0xC100u, 0x1C000u, 0x18000u
};
// dense list of the 49 adjacent (i,j) pairs, packed (i<<8)|j
__device__ __constant__ unsigned short PAIR[49] = {
    0x0000,0x0001,0x0004,0x0007, 0x0100,0x0101,0x0102, 0x0201,0x0202,0x0203,
    0x0302,0x0303, 0x0400,0x0404,0x0405, 0x0504,0x0505,0x0506, 0x0605,0x0606,
    0x0700,0x0707,0x0708, 0x0807,0x0808,0x0809,0x080B,0x080E, 0x0908,0x0909,0x090A,
    0x0A09,0x0A0A, 0x0B08,0x0B0B,0x0B0C, 0x0C0B,0x0C0C,0x0C0D, 0x0D0C,0x0D0D,
    0x0E08,0x0E0E,0x0E0F, 0x0F0E,0x0F0F,0x0F10, 0x100F,0x1010
};

__device__ __forceinline__ ushort_t f2bf(float v){
    uint_t u = __float_as_uint(v);
    uint_t r = (u + 0x7FFFu + ((u >> 16) & 1u)) >> 16;
    return (ushort_t)r;
}
__device__ __forceinline__ float bf2f(ushort_t h){ return __uint_as_float(((uint_t)h) << 16); }
__device__ __forceinline__ float bflo(uint_t u){ return __uint_as_float(u << 16); }
__device__ __forceinline__ float bfhi(uint_t u){ return __uint_as_float(u & 0xFFFF0000u); }
__device__ __forceinline__ float lrelu02(float u){ return fmaxf(u, 0.f) + 0.2f*fminf(u, 0.f); }
__device__ __forceinline__ float gelu_exact(float x){ return 0.5f*x*(1.f + erff(x*0.70710678118654752f)); }

// per-row LN stats over 17x128 fp32 tile (stride XS) -> sMU/sRS ; caller syncs
__device__ __forceinline__ void ln_stats(const float* sXp, float* sMU, float* sRS, int t){
    if (t < 136){
        int g = t >> 3, w = t & 7;
        const float4* row = (const float4*)(sXp + g*XS);
        float s = 0.f, q = 0.f;
        #pragma unroll
        for (int cc = 0; cc < 4; cc++){
            float4 v = row[w*4 + cc];
            s += v.x + v.y + v.z + v.w;
            q += v.x*v.x + v.y*v.y + v.z*v.z + v.w*v.w;
        }
        s += __shfl_xor(s, 1); s += __shfl_xor(s, 2); s += __shfl_xor(s, 4);
        q += __shfl_xor(q, 1); q += __shfl_xor(q, 2); q += __shfl_xor(q, 4);
        if (w == 0){
            float m = s * (1.f/128.f);
            float var = q * (1.f/128.f) - m*m;
            sMU[g] = m;
            sRS[g] = rsqrtf(var + 1e-5f);
        }
    }
}

// prep: WT[f][k] bf16 hi/lo (f: 0..255 w1-col, 256..511 w2-col, 512..639 vw-col) + bcat
__global__ void prep_kernel(const float* __restrict__ w1, const float* __restrict__ b1,
                            const float* __restrict__ w2, const float* __restrict__ b2,
                            const float* __restrict__ vw, const float* __restrict__ vb,
                            ushort_t* __restrict__ whi, ushort_t* __restrict__ wlo,
                            float* __restrict__ bcat){
    int gid = blockIdx.x*256 + threadIdx.x;
    if (gid < 640*128){
        int f = gid >> 7, k = gid & 127;
        float v;
        if (f < 256)      v = w1[k*256 + f];
        else if (f < 512) v = w2[k*256 + (f-256)];
        else              v = vw[k*128 + (f-512)];
        ushort_t h = f2bf(v);
        whi[gid] = h;
        wlo[gid] = f2bf(v - bf2f(h));
    }
    if (gid < 640){
        float b;
        if (gid < 256)      b = b1[gid];
        else if (gid < 512) b = b2[gid-256];
        else                b = vb[gid-512];
        bcat[gid] = b;
    }
}

__global__ __launch_bounds__(256, 2)
void appnp_kernel(const float* __restrict__ x,
                  const float* __restrict__ og, const float* __restrict__ ob,
                  const float* __restrict__ lg, const float* __restrict__ lb,
                  const float* __restrict__ aw, const float* __restrict__ ab,
                  const float* __restrict__ psw, const float* __restrict__ psb,
                  const ushort_t* __restrict__ whi, const ushort_t* __restrict__ wlo,
                  const float* __restrict__ bcat,
                  float* __restrict__ out)
{
    __shared__ __align__(16) float smem[16312];   // 65,248 B <= 64KB+... fits, 2 blocks/CU
    float* sX  = smem;                 // 2244
    float* sX0 = smem + 2244;          // 2244
    float* sV  = smem + 4488;          // 2244
    float* sS  = smem + 6732;          // 680
    float* sMU = smem + 7412;          // 20
    float* sRS = smem + 7432;          // 20
    float* sK  = smem + 7452;          // 20
    ushort_t* sLb = (ushort_t*)(smem + 7472);   // 17*264 ush
    ushort_t* sRb = (ushort_t*)(smem + 9716);   // 17*264 ush
    ushort_t* sXh = (ushort_t*)(smem + 11960);  // 32*136 ush
    ushort_t* sXl = (ushort_t*)(smem + 14136);  // 32*136 ush

    const int t = threadIdx.x;
    const long long base = (long long)blockIdx.x * TOKE;

    // ---- load x ; zero MFMA pad rows 17..31 of sXh/sXl ----
    for (int idx = t; idx < TOKE; idx += 256){
        sX[(idx>>7)*XS + (idx&127)] = x[base + idx];
    }
    {
        uint_t* ph = (uint_t*)(sXh + NJ*XBS);
        uint_t* pl = (uint_t*)(sXl + NJ*XBS);
        for (int idx = t; idx < 1020; idx += 256){ ph[idx] = 0u; pl[idx] = 0u; }
    }
    __syncthreads();

    // ---- outer LN -> sX (in place) and sX0 ----
    ln_stats(sX, sMU, sRS, t);
    __syncthreads();
    for (int idx = t; idx < 544; idx += 256){
        int r = idx >> 5, c = (idx & 31) << 2;
        float mu = sMU[r], rs = sRS[r];
        float4 v = *(const float4*)(sX + r*XS + c);
        float4 g = *(const float4*)(og + c);
        float4 b = *(const float4*)(ob + c);
        v.x = (v.x-mu)*rs*g.x + b.x;  v.y = (v.y-mu)*rs*g.y + b.y;
        v.z = (v.z-mu)*rs*g.z + b.z;  v.w = (v.w-mu)*rs*g.w + b.w;
        *(float4*)(sX  + r*XS + c) = v;
        *(float4*)(sX0 + r*XS + c) = v;
    }
    __syncthreads();

    const int wave = t >> 6, lane = t & 63, l16 = lane & 15, quad = lane >> 4;

    for (int it = 0; it < 4; it++){
        // ---- (a) inner LN: sX -> sXh/sXl (bf16 hi/lo), sX preserved ----
        ln_stats(sX, sMU, sRS, t);
        __syncthreads();
        for (int idx = t; idx < 544; idx += 256){
            int r = idx >> 5, c = (idx & 31) << 2;
            float mu = sMU[r], rs = sRS[r];
            float4 v = *(const float4*)(sX + r*XS + c);
            float4 g = *(const float4*)(lg + c);
            float4 b = *(const float4*)(lb + c);
            float n0 = (v.x-mu)*rs*g.x + b.x, n1 = (v.y-mu)*rs*g.y + b.y;
            float n2 = (v.z-mu)*rs*g.z + b.z, n3 = (v.w-mu)*rs*g.w + b.w;
            ushort_t h0 = f2bf(n0), h1 = f2bf(n1), h2 = f2bf(n2), h3 = f2bf(n3);
            uint2 ph; ph.x = (uint_t)h0 | ((uint_t)h1 << 16); ph.y = (uint_t)h2 | ((uint_t)h3 << 16);
            ushort_t e0 = f2bf(n0 - bf2f(h0)), e1 = f2bf(n1 - bf2f(h1));
            ushort_t e2 = f2bf(n2 - bf2f(h2)), e3 = f2bf(n3 - bf2f(h3));
            uint2 pl; pl.x = (uint_t)e0 | ((uint_t)e1 << 16); pl.y = (uint_t)e2 | ((uint_t)e3 << 16);
            *(uint2*)(sXh + r*XBS + c) = ph;
            *(uint2*)(sXl + r*XBS + c) = pl;
        }
        __syncthreads();

        // ---- (b) MFMA GEMM: D(640 x 17) = WT(640x128) @ xn^T ; split bf16 hi/lo ----
        for (int nt = 0; nt < 2; nt++){
            const ushort_t* bh = sXh + (nt*16 + l16)*XBS + quad*8;
            const ushort_t* bl = sXl + (nt*16 + l16)*XBS + quad*8;
            short8 Bh[4], Bl[4];
            #pragma unroll
            for (int ks = 0; ks < 4; ks++){
                Bh[ks] = *(const short8*)(bh + ks*32);
                Bl[ks] = *(const short8*)(bl + ks*32);
            }
            #pragma unroll 2
            for (int ft = 0; ft < 10; ft++){
                int f0 = (wave*10 + ft) << 4;
                const ushort_t* ah = whi + (f0 + l16)*128 + quad*8;
                const ushort_t* al = wlo + (f0 + l16)*128 + quad*8;
                short8 Ah[4], Al[4];
                #pragma unroll
                for (int ks = 0; ks < 4; ks++){
                    Ah[ks] = *(const short8*)(ah + ks*32);
                    Al[ks] = *(const short8*)(al + ks*32);
                }
                float4 bb = *(const float4*)(bcat + f0 + quad*4);
                f32x4 acc; acc[0] = bb.x; acc[1] = bb.y; acc[2] = bb.z; acc[3] = bb.w;
                #pragma unroll
                for (int ks = 0; ks < 4; ks++){
                    acc = __builtin_amdgcn_mfma_f32_16x16x32_bf16(Ah[ks], Bh[ks], acc, 0, 0, 0);
                    acc = __builtin_amdgcn_mfma_f32_16x16x32_bf16(Ah[ks], Bl[ks], acc, 0, 0, 0);
                    acc = __builtin_amdgcn_mfma_f32_16x16x32_bf16(Al[ks], Bh[ks], acc, 0, 0, 0);
                }
                int r = nt*16 + l16;
                if (r < NJ){
                    int fb = f0 + quad*4;
                    if (f0 < 512){
                        ushort_t* dst = (f0 < 256) ? (sLb + r*LBS + fb) : (sRb + r*LBS + (fb - 256));
                        uint2 p;
                        p.x = (uint_t)f2bf(acc[0]) | ((uint_t)f2bf(acc[1]) << 16);
                        p.y = (uint_t)f2bf(acc[2]) | ((uint_t)f2bf(acc[3]) << 16);
                        *(uint2*)dst = p;
                    } else {
                        float4 o; o.x = acc[0]; o.y = acc[1]; o.z = acc[2]; o.w = acc[3];
                        *(float4*)(sV + r*XS + (fb - 512)) = o;
                    }
                }
            }
        }
        __syncthreads();

        // ---- (c) attention scores: dense 49-pair list x 2 heads ----
        if (t < 98){
            int h = (t >= 49);
            int p = t - 49*h;
            unsigned short pr = PAIR[p];
            int i = pr >> 8, j = pr & 255;
            const uint4* lp = (const uint4*)(sLb + i*LBS + h*128);
            const uint4* rp = (const uint4*)(sRb + j*LBS + h*128);
            float acc = 0.f;
            #pragma unroll
            for (int d = 0; d < 16; d++){
                uint4 lu = lp[d], ru = rp[d];
                float4 p0 = *(const float4*)(psw + d*8);
                float4 p1 = *(const float4*)(psw + d*8 + 4);
                acc += lrelu02(bflo(lu.x) + bflo(ru.x)) * p0.x;
                acc += lrelu02(bfhi(lu.x) + bfhi(ru.x)) * p0.y;
                acc += lrelu02(bflo(lu.y) + bflo(ru.y)) * p0.z;
                acc += lrelu02(bfhi(lu.y) + bfhi(ru.y)) * p0.w;
                acc += lrelu02(bflo(lu.z) + bflo(ru.z)) * p1.x;
                acc += lrelu02(bfhi(lu.z) + bfhi(ru.z)) * p1.y;
                acc += lrelu02(bflo(lu.w) + bflo(ru.w)) * p1.z;
                acc += lrelu02(bfhi(lu.w) + bfhi(ru.w)) * p1.w;
            }
            sS[(h*NJ + i)*SS + j] = acc + psb[0];
        }
        __syncthreads();

        // ---- (d) masked softmax (t<34) + skip gate (t 34..50) ----
        if (t < 34){
            int h = (t >= NJ);
            int i = t - h*NJ;
            float* sp = sS + (h*NJ + i)*SS;
            unsigned int m = ADJM[i];
            float mx = -1e30f;
            #pragma unroll
            for (int j = 0; j < NJ; j++) if ((m >> j) & 1u) mx = fmaxf(mx, sp[j]);
            float pv[NJ]; float sum = 0.f;
            #pragma unroll
            for (int j = 0; j < NJ; j++){
                if ((m >> j) & 1u){ pv[j] = expf(sp[j] - mx); sum += pv[j]; }
                else pv[j] = 0.f;
            }
            float inv = 1.f / sum;
            #pragma unroll
            for (int j = 0; j < NJ; j++) sp[j] = pv[j]*inv;
        } else if (t < 51){
            int i = t - 34;
            const uint4* xh = (const uint4*)(sXh + i*XBS);
            const uint4* xl = (const uint4*)(sXl + i*XBS);
            float acc = 0.f;
            #pragma unroll
            for (int d = 0; d < 16; d++){
                uint4 uh = xh[d], ul = xl[d];
                float4 a0 = *(const float4*)(aw + d*8);
                float4 a1 = *(const float4*)(aw + d*8 + 4);
                acc += (bflo(uh.x) + bflo(ul.x)) * a0.x;
                acc += (bfhi(uh.x) + bfhi(ul.x)) * a0.y;
                acc += (bflo(uh.y) + bflo(ul.y)) * a0.z;
                acc += (bfhi(uh.y) + bfhi(ul.y)) * a0.w;
                acc += (bflo(uh.z) + bflo(ul.z)) * a1.x;
                acc += (bfhi(uh.z) + bfhi(ul.z)) * a1.y;
                acc += (bflo(uh.w) + bflo(ul.w)) * a1.z;
                acc += (bfhi(uh.w) + bfhi(ul.w)) * a1.w;
            }
            sK[i] = 1.f / (1.f + expf(-(acc + ab[0])));
        }
        __syncthreads();

        // ---- (e) PV + gelu + blend -> new x in sX ----
        for (int idx = t; idx < 544; idx += 256){
            int r = idx >> 5, cg = idx & 31;
            int c = cg << 2, h = cg >> 4;
            const float* sp = sS + (h*NJ + r)*SS;
            float a0 = 0.f, a1 = 0.f, a2 = 0.f, a3 = 0.f;
            #pragma unroll
            for (int j = 0; j < NJ; j++){
                float pj = sp[j];
                float4 vv = *(const float4*)(sV + j*XS + c);
                a0 += pj*vv.x; a1 += pj*vv.y; a2 += pj*vv.z; a3 += pj*vv.w;
            }
            a0 = gelu_exact(a0); a1 = gelu_exact(a1); a2 = gelu_exact(a2); a3 = gelu_exact(a3);
            float sk = sK[r];
            float4 x0 = *(const float4*)(sX0 + r*XS + c);
            float4 nx;
            nx.x = (1.f-sk)*a0 + sk*x0.x;  nx.y = (1.f-sk)*a1 + sk*x0.y;
            nx.z = (1.f-sk)*a2 + sk*x0.z;  nx.w = (1.f-sk)*a3 + sk*x0.w;
            *(float4*)(sX + r*XS + c) = nx;
        }
        __syncthreads();
    }

    // ---- store ----
    for (int idx = t; idx < TOKE; idx += 256){
        out[base + idx] = sX[(idx>>7)*XS + (idx&127)];
    }
}

extern "C" void kernel_launch(void* const* d_in, const int* in_sizes, int n_in,
                              void* d_out, int out_size, void* d_ws, size_t ws_size,
                              hipStream_t stream) {
    const float* x   = (const float*)d_in[0];
    const float* og  = (const float*)d_in[1];
    const float* ob  = (const float*)d_in[2];
    const float* lg  = (const float*)d_in[3];
    const float* lb  = (const float*)d_in[4];
    const float* aw  = (const float*)d_in[5];
    const float* ab  = (const float*)d_in[6];
    const float* w1  = (const float*)d_in[7];
    const float* b1  = (const float*)d_in[8];
    const float* w2  = (const float*)d_in[9];
    const float* b2  = (const float*)d_in[10];
    const float* psw = (const float*)d_in[11];
    const float* psb = (const float*)d_in[12];
    const float* vw  = (const float*)d_in[13];
    const float* vb  = (const float*)d_in[14];
    float* out = (float*)d_out;

    // workspace: WThi (640*128 bf16), WTlo (640*128 bf16), bcat (640 f32) = 330,240 B
    ushort_t* whi = (ushort_t*)d_ws;
    ushort_t* wlo = whi + 640*128;
    float* bcat = (float*)(wlo + 640*128);

    prep_kernel<<<dim3(320), dim3(256), 0, stream>>>(w1, b1, w2, b2, vw, vb, whi, wlo, bcat);

    int BT = in_sizes[0] / TOKE;   // 3888 tokens
    appnp_kernel<<<dim3(BT), dim3(256), 0, stream>>>(
        x, og, ob, lg, lb, aw, ab, psw, psb, whi, wlo, bcat, out);
}

// Round 5
// 1098.754 us; speedup vs baseline: 1.3347x; 1.3347x over previous
//
#include <hip/hip_runtime.h>
#include <math.h>

#define NJ 17
#define DD 128
#define XS 132      // fp32 row stride for sX/sV/sX0 (floats)
#define LBS 264     // ushort row stride for sLb/sRb (bf16)
#define XBS 136     // ushort row stride for sXh/sXl (bf16)
#define SS 20       // score row stride
#define TOKE (NJ*DD)
#define NTHREADS 512

typedef unsigned short ushort_t;
typedef unsigned int uint_t;
typedef __attribute__((ext_vector_type(8))) short short8;
typedef __attribute__((ext_vector_type(4))) float f32x4;

// adjacency bitmasks (both dirs + diag)
__device__ __constant__ unsigned int ADJM[NJ] = {
    0x93u, 0x7u, 0xEu, 0xCu, 0x31u, 0x70u, 0x60u,
    0x181u, 0x4B80u, 0x700u, 0x600u, 0x1900u, 0x3800u, 0x3000u,
    0xC100u, 0x1C000u, 0x18000u
};
// dense list of the 49 adjacent (i,j) pairs, packed (i<<8)|j
__device__ __constant__ unsigned short PAIR[49] = {
    0x0000,0x0001,0x0004,0x0007, 0x0100,0x0101,0x0102, 0x0201,0x0202,0x0203,
    0x0302,0x0303, 0x0400,0x0404,0x0405, 0x0504,0x0505,0x0506, 0x0605,0x0606,
    0x0700,0x0707,0x0708, 0x0807,0x0808,0x0809,0x080B,0x080E, 0x0908,0x0909,0x090A,
    0x0A09,0x0A0A, 0x0B08,0x0B0B,0x0B0C, 0x0C0B,0x0C0C,0x0C0D, 0x0D0C,0x0D0D,
    0x0E08,0x0E0E,0x0E0F, 0x0F0E,0x0F0F,0x0F10, 0x100F,0x1010
};

__device__ __forceinline__ ushort_t f2bf(float v){
    uint_t u = __float_as_uint(v);
    uint_t r = (u + 0x7FFFu + ((u >> 16) & 1u)) >> 16;
    return (ushort_t)r;
}
__device__ __forceinline__ float bf2f(ushort_t h){ return __uint_as_float(((uint_t)h) << 16); }
__device__ __forceinline__ float bflo(uint_t u){ return __uint_as_float(u << 16); }
__device__ __forceinline__ float bfhi(uint_t u){ return __uint_as_float(u & 0xFFFF0000u); }
__device__ __forceinline__ float lrelu02(float u){ return fmaxf(u, 0.f) + 0.2f*fminf(u, 0.f); }
__device__ __forceinline__ float gelu_exact(float x){ return 0.5f*x*(1.f + erff(x*0.70710678118654752f)); }

// per-row LN stats over 17x128 fp32 tile (stride XS) -> sMU/sRS ; caller syncs
__device__ __forceinline__ void ln_stats(const float* sXp, float* sMU, float* sRS, int t){
    if (t < 136){
        int g = t >> 3, w = t & 7;
        const float4* row = (const float4*)(sXp + g*XS);
        float s = 0.f, q = 0.f;
        #pragma unroll
        for (int cc = 0; cc < 4; cc++){
            float4 v = row[w*4 + cc];
            s += v.x + v.y + v.z + v.w;
            q += v.x*v.x + v.y*v.y + v.z*v.z + v.w*v.w;
        }
        s += __shfl_xor(s, 1); s += __shfl_xor(s, 2); s += __shfl_xor(s, 4);
        q += __shfl_xor(q, 1); q += __shfl_xor(q, 2); q += __shfl_xor(q, 4);
        if (w == 0){
            float m = s * (1.f/128.f);
            float var = q * (1.f/128.f) - m*m;
            sMU[g] = m;
            sRS[g] = rsqrtf(var + 1e-5f);
        }
    }
}

// prep: WT[f][k] bf16 hi/lo (f: 0..255 w1-col, 256..511 w2-col, 512..639 vw-col) + bcat
__global__ void prep_kernel(const float* __restrict__ w1, const float* __restrict__ b1,
                            const float* __restrict__ w2, const float* __restrict__ b2,
                            const float* __restrict__ vw, const float* __restrict__ vb,
                            ushort_t* __restrict__ whi, ushort_t* __restrict__ wlo,
                            float* __restrict__ bcat){
    int gid = blockIdx.x*256 + threadIdx.x;
    if (gid < 640*128){
        int f = gid >> 7, k = gid & 127;
        float v;
        if (f < 256)      v = w1[k*256 + f];
        else if (f < 512) v = w2[k*256 + (f-256)];
        else              v = vw[k*128 + (f-512)];
        ushort_t h = f2bf(v);
        whi[gid] = h;
        wlo[gid] = f2bf(v - bf2f(h));
    }
    if (gid < 640){
        float b;
        if (gid < 256)      b = b1[gid];
        else if (gid < 512) b = b2[gid-256];
        else                b = vb[gid-512];
        bcat[gid] = b;
    }
}

__global__ __launch_bounds__(NTHREADS, 2)
void appnp_kernel(const float* __restrict__ x,
                  const float* __restrict__ og, const float* __restrict__ ob,
                  const float* __restrict__ lg, const float* __restrict__ lb,
                  const float* __restrict__ aw, const float* __restrict__ ab,
                  const float* __restrict__ psw, const float* __restrict__ psb,
                  const ushort_t* __restrict__ whi, const ushort_t* __restrict__ wlo,
                  const float* __restrict__ bcat,
                  float* __restrict__ out)
{
    __shared__ __align__(16) float smem[15430];   // 61,720 B < 64 KiB static limit
    float*    sX   = smem;                        // [0,2244)       fp32 state x
    float*    sV   = smem + 2248;                 // [2248,4492)    fp32 V
    ushort_t* sXh  = (ushort_t*)(smem + 4492);    // 17*136 ush     xn bf16-hi
    ushort_t* sXl  = (ushort_t*)(smem + 5648);    // 17*136 ush     xn bf16-lo
    ushort_t* sLb  = (ushort_t*)(smem + 6804);    // 17*264 ush     l bf16
    ushort_t* sRb  = (ushort_t*)(smem + 9048);    // 17*264 ush     r bf16
    float*    sX0  = smem + 11292;                // [11292,13536)  fp32 x0
    float*    sS   = smem + 13536;                // 680 (scores)
    float*    sMU  = smem + 14216;                // 20
    float*    sRS  = smem + 14236;                // 20
    float*    sK   = smem + 14256;                // 20
    float*    sLG  = smem + 14276;                // 128
    float*    sLBt = smem + 14404;                // 128
    float*    sPW  = smem + 14532;                // 128
    float*    sAW  = smem + 14660;                // 128
    float*    sBC  = smem + 14788;                // 642 (bcat + psb + ab)

    const int t = threadIdx.x;
    const int wave = t >> 6, lane = t & 63, l16 = lane & 15, quad = lane >> 4;
    const long long base = (long long)blockIdx.x * TOKE;

    // ---- weight preamble: wave's 80-feature strip (hi+lo) into registers ----
    short8 Wh[5][4], Wl[5][4];
    #pragma unroll
    for (int ft = 0; ft < 5; ft++){
        const ushort_t* ah = whi + (wave*80 + ft*16 + l16)*128 + quad*8;
        const ushort_t* al = wlo + (wave*80 + ft*16 + l16)*128 + quad*8;
        #pragma unroll
        for (int ks = 0; ks < 4; ks++){
            Wh[ft][ks] = *(const short8*)(ah + ks*32);
            Wl[ft][ks] = *(const short8*)(al + ks*32);
        }
    }

    // ---- stage small params into LDS ----
    if (t < 128){
        sLG[t]  = lg[t];
        sLBt[t] = lb[t];
        sPW[t]  = psw[t];
        sAW[t]  = aw[t];
    }
    for (int i = t; i < 640; i += NTHREADS) sBC[i] = bcat[i];
    if (t == 0){ sBC[640] = psb[0]; sBC[641] = ab[0]; }

    // ---- load x ----
    for (int idx = t; idx < TOKE; idx += NTHREADS){
        sX[(idx>>7)*XS + (idx&127)] = x[base + idx];
    }
    __syncthreads();

    // ---- outer LN -> sX (in place, fp32) and sX0 (fp32) ----
    ln_stats(sX, sMU, sRS, t);
    __syncthreads();
    for (int idx = t; idx < 544; idx += NTHREADS){
        int r = idx >> 5, c = (idx & 31) << 2;
        float mu = sMU[r], rs = sRS[r];
        float4 v = *(const float4*)(sX + r*XS + c);
        float4 g = *(const float4*)(og + c);
        float4 b = *(const float4*)(ob + c);
        v.x = (v.x-mu)*rs*g.x + b.x;  v.y = (v.y-mu)*rs*g.y + b.y;
        v.z = (v.z-mu)*rs*g.z + b.z;  v.w = (v.w-mu)*rs*g.w + b.w;
        *(float4*)(sX  + r*XS + c) = v;
        *(float4*)(sX0 + r*XS + c) = v;
    }
    __syncthreads();

    for (int it = 0; it < 4; it++){
        // ---- (a) inner LN: sX -> sXh/sXl (bf16 hi/lo), sX preserved ----
        ln_stats(sX, sMU, sRS, t);
        __syncthreads();
        for (int idx = t; idx < 544; idx += NTHREADS){
            int r = idx >> 5, c = (idx & 31) << 2;
            float mu = sMU[r], rs = sRS[r];
            float4 v = *(const float4*)(sX + r*XS + c);
            float4 g = *(const float4*)(sLG + c);
            float4 b = *(const float4*)(sLBt + c);
            float n0 = (v.x-mu)*rs*g.x + b.x, n1 = (v.y-mu)*rs*g.y + b.y;
            float n2 = (v.z-mu)*rs*g.z + b.z, n3 = (v.w-mu)*rs*g.w + b.w;
            ushort_t h0 = f2bf(n0), h1 = f2bf(n1), h2 = f2bf(n2), h3 = f2bf(n3);
            uint2 ph; ph.x = (uint_t)h0 | ((uint_t)h1 << 16); ph.y = (uint_t)h2 | ((uint_t)h3 << 16);
            ushort_t e0 = f2bf(n0 - bf2f(h0)), e1 = f2bf(n1 - bf2f(h1));
            ushort_t e2 = f2bf(n2 - bf2f(h2)), e3 = f2bf(n3 - bf2f(h3));
            uint2 pl; pl.x = (uint_t)e0 | ((uint_t)e1 << 16); pl.y = (uint_t)e2 | ((uint_t)e3 << 16);
            *(uint2*)(sXh + r*XBS + c) = ph;
            *(uint2*)(sXl + r*XBS + c) = pl;
        }
        __syncthreads();

        // ---- (b) MFMA GEMM: D(640 x 17) = W(regs, bf16 hi/lo) @ xn^T(hi+lo) ----
        #pragma unroll
        for (int nt = 0; nt < 2; nt++){
            int rbase = nt*16 + l16;
            // cols >= NJ read a valid junk row (their D columns are discarded)
            int rr = (rbase < NJ) ? rbase : (rbase - 16);
            const ushort_t* bhp = sXh + rr*XBS + quad*8;
            const ushort_t* blp = sXl + rr*XBS + quad*8;
            short8 Bh[4], Bl[4];
            #pragma unroll
            for (int ks = 0; ks < 4; ks++){
                Bh[ks] = *(const short8*)(bhp + ks*32);
                Bl[ks] = *(const short8*)(blp + ks*32);
            }
            #pragma unroll
            for (int ft = 0; ft < 5; ft++){
                int f0 = wave*80 + ft*16;
                float4 bb = *(const float4*)(sBC + f0 + quad*4);
                f32x4 acc; acc[0] = bb.x; acc[1] = bb.y; acc[2] = bb.z; acc[3] = bb.w;
                #pragma unroll
                for (int ks = 0; ks < 4; ks++){
                    acc = __builtin_amdgcn_mfma_f32_16x16x32_bf16(Wh[ft][ks], Bh[ks], acc, 0, 0, 0);
                    acc = __builtin_amdgcn_mfma_f32_16x16x32_bf16(Wh[ft][ks], Bl[ks], acc, 0, 0, 0);
                    acc = __builtin_amdgcn_mfma_f32_16x16x32_bf16(Wl[ft][ks], Bh[ks], acc, 0, 0, 0);
                }
                if (rbase < NJ){
                    int fb = f0 + quad*4;
                    if (f0 < 512){
                        ushort_t* dst = (f0 < 256) ? (sLb + rbase*LBS + fb) : (sRb + rbase*LBS + (fb - 256));
                        uint2 p;
                        p.x = (uint_t)f2bf(acc[0]) | ((uint_t)f2bf(acc[1]) << 16);
                        p.y = (uint_t)f2bf(acc[2]) | ((uint_t)f2bf(acc[3]) << 16);
                        *(uint2*)dst = p;
                    } else {
                        float4 o; o.x = acc[0]; o.y = acc[1]; o.z = acc[2]; o.w = acc[3];
                        *(float4*)(sV + rbase*XS + (fb - 512)) = o;
                    }
                }
            }
        }
        __syncthreads();

        // ---- (c) attention scores: dense 49-pair list x 2 heads ----
        if (t < 98){
            int h = (t >= 49);
            int p = t - 49*h;
            unsigned short pr = PAIR[p];
            int i = pr >> 8, j = pr & 255;
            const uint4* lp = (const uint4*)(sLb + i*LBS + h*128);
            const uint4* rp = (const uint4*)(sRb + j*LBS + h*128);
            float acc = 0.f;
            #pragma unroll
            for (int d = 0; d < 16; d++){
                uint4 lu = lp[d], ru = rp[d];
                float4 p0 = *(const float4*)(sPW + d*8);
                float4 p1 = *(const float4*)(sPW + d*8 + 4);
                acc += lrelu02(bflo(lu.x) + bflo(ru.x)) * p0.x;
                acc += lrelu02(bfhi(lu.x) + bfhi(ru.x)) * p0.y;
                acc += lrelu02(bflo(lu.y) + bflo(ru.y)) * p0.z;
                acc += lrelu02(bfhi(lu.y) + bfhi(ru.y)) * p0.w;
                acc += lrelu02(bflo(lu.z) + bflo(ru.z)) * p1.x;
                acc += lrelu02(bfhi(lu.z) + bfhi(ru.z)) * p1.y;
                acc += lrelu02(bflo(lu.w) + bflo(ru.w)) * p1.z;
                acc += lrelu02(bfhi(lu.w) + bfhi(ru.w)) * p1.w;
            }
            sS[(h*NJ + i)*SS + j] = acc + sBC[640];
        }
        __syncthreads();

        // ---- (d) masked softmax (t<34) + skip gate (t 34..50) ----
        if (t < 34){
            int h = (t >= NJ);
            int i = t - h*NJ;
            float* sp = sS + (h*NJ + i)*SS;
            unsigned int m = ADJM[i];
            float mx = -1e30f;
            #pragma unroll
            for (int j = 0; j < NJ; j++) if ((m >> j) & 1u) mx = fmaxf(mx, sp[j]);
            float pv[NJ]; float sum = 0.f;
            #pragma unroll
            for (int j = 0; j < NJ; j++){
                if ((m >> j) & 1u){ pv[j] = expf(sp[j] - mx); sum += pv[j]; }
                else pv[j] = 0.f;
            }
            float inv = 1.f / sum;
            #pragma unroll
            for (int j = 0; j < NJ; j++) sp[j] = pv[j]*inv;
        } else if (t < 51){
            int i = t - 34;
            const uint4* xh = (const uint4*)(sXh + i*XBS);
            const uint4* xl = (const uint4*)(sXl + i*XBS);
            float acc = 0.f;
            #pragma unroll
            for (int d = 0; d < 16; d++){
                uint4 uh = xh[d], ul = xl[d];
                float4 a0 = *(const float4*)(sAW + d*8);
                float4 a1 = *(const float4*)(sAW + d*8 + 4);
                acc += (bflo(uh.x) + bflo(ul.x)) * a0.x;
                acc += (bfhi(uh.x) + bfhi(ul.x)) * a0.y;
                acc += (bflo(uh.y) + bflo(ul.y)) * a0.z;
                acc += (bfhi(uh.y) + bfhi(ul.y)) * a0.w;
                acc += (bflo(uh.z) + bflo(ul.z)) * a1.x;
                acc += (bfhi(uh.z) + bfhi(ul.z)) * a1.y;
                acc += (bflo(uh.w) + bflo(ul.w)) * a1.z;
                acc += (bfhi(uh.w) + bfhi(ul.w)) * a1.w;
            }
            sK[i] = 1.f / (1.f + expf(-(acc + sBC[641])));
        }
        __syncthreads();

        // ---- (e) PV + gelu + blend (x0 fp32) -> new x in sX ----
        for (int idx = t; idx < 544; idx += NTHREADS){
            int r = idx >> 5, cg = idx & 31;
            int c = cg << 2, h = cg >> 4;
            const float* sp = sS + (h*NJ + r)*SS;
            float a0 = 0.f, a1 = 0.f, a2 = 0.f, a3 = 0.f;
            #pragma unroll
            for (int j = 0; j < NJ; j++){
                float pj = sp[j];
                float4 vv = *(const float4*)(sV + j*XS + c);
                a0 += pj*vv.x; a1 += pj*vv.y; a2 += pj*vv.z; a3 += pj*vv.w;
            }
            a0 = gelu_exact(a0); a1 = gelu_exact(a1); a2 = gelu_exact(a2); a3 = gelu_exact(a3);
            float sk = sK[r];
            float4 x0v = *(const float4*)(sX0 + r*XS + c);
            float4 nx;
            nx.x = (1.f-sk)*a0 + sk*x0v.x;  nx.y = (1.f-sk)*a1 + sk*x0v.y;
            nx.z = (1.f-sk)*a2 + sk*x0v.z;  nx.w = (1.f-sk)*a3 + sk*x0v.w;
            *(float4*)(sX + r*XS + c) = nx;
        }
        __syncthreads();
    }

    // ---- store ----
    for (int idx = t; idx < TOKE; idx += NTHREADS){
        out[base + idx] = sX[(idx>>7)*XS + (idx&127)];
    }
}

extern "C" void kernel_launch(void* const* d_in, const int* in_sizes, int n_in,
                              void* d_out, int out_size, void* d_ws, size_t ws_size,
                              hipStream_t stream) {
    const float* x   = (const float*)d_in[0];
    const float* og  = (const float*)d_in[1];
    const float* ob  = (const float*)d_in[2];
    const float* lg  = (const float*)d_in[3];
    const float* lb  = (const float*)d_in[4];
    const float* aw  = (const float*)d_in[5];
    const float* ab  = (const float*)d_in[6];
    const float* w1  = (const float*)d_in[7];
    const float* b1  = (const float*)d_in[8];
    const float* w2  = (const float*)d_in[9];
    const float* b2  = (const float*)d_in[10];
    const float* psw = (const float*)d_in[11];
    const float* psb = (const float*)d_in[12];
    const float* vw  = (const float*)d_in[13];
    const float* vb  = (const float*)d_in[14];
    float* out = (float*)d_out;

    // workspace: whi (640*128 bf16) + wlo (640*128 bf16) + bcat (640 f32) = 330,240 B
    ushort_t* whi = (ushort_t*)d_ws;
    ushort_t* wlo = whi + 640*128;
    float* bcat = (float*)(wlo + 640*128);

    prep_kernel<<<dim3(320), dim3(256), 0, stream>>>(w1, b1, w2, b2, vw, vb, whi, wlo, bcat);

    int BT = in_sizes[0] / TOKE;   // 3888 tokens
    appnp_kernel<<<dim3(BT), dim3(NTHREADS), 0, stream>>>(
        x, og, ob, lg, lb, aw, ab, psw, psb, whi, wlo, bcat, out);
}

// Round 6
// 1094.214 us; speedup vs baseline: 1.3402x; 1.0041x over previous
//
#include <hip/hip_runtime.h>
#include <math.h>

#define NJ 17
#define DD 128
#define XS 132      // fp32 row stride for sX/sV/sX0 (floats)
#define LBS 264     // ushort row stride for sLb/sRb (bf16)
#define XBS 136     // ushort row stride for sXh/sXl (bf16)
#define SS 20       // score row stride
#define TOKE (NJ*DD)
#define NTHREADS 512

typedef unsigned short ushort_t;
typedef unsigned int uint_t;
typedef __attribute__((ext_vector_type(8))) short short8;
typedef __attribute__((ext_vector_type(4))) float f32x4;

// adjacency bitmasks (both dirs + diag)
__device__ __constant__ unsigned int ADJM[NJ] = {
    0x93u, 0x7u, 0xEu, 0xCu, 0x31u, 0x70u, 0x60u,
    0x181u, 0x4B80u, 0x700u, 0x600u, 0x1900u, 0x3800u, 0x3000u,
    0xC100u, 0x1C000u, 0x18000u
};
// dense list of the 49 adjacent (i,j) pairs, packed (i<<8)|j
__device__ __constant__ unsigned short PAIR[49] = {
    0x0000,0x0001,0x0004,0x0007, 0x0100,0x0101,0x0102, 0x0201,0x0202,0x0203,
    0x0302,0x0303, 0x0400,0x0404,0x0405, 0x0504,0x0505,0x0506, 0x0605,0x0606,
    0x0700,0x0707,0x0708, 0x0807,0x0808,0x0809,0x080B,0x080E, 0x0908,0x0909,0x090A,
    0x0A09,0x0A0A, 0x0B08,0x0B0B,0x0B0C, 0x0C0B,0x0C0C,0x0C0D, 0x0D0C,0x0D0D,
    0x0E08,0x0E0E,0x0E0F, 0x0F0E,0x0F0F,0x0F10, 0x100F,0x1010
};

__device__ __forceinline__ ushort_t f2bf(float v){
    uint_t u = __float_as_uint(v);
    uint_t r = (u + 0x7FFFu + ((u >> 16) & 1u)) >> 16;
    return (ushort_t)r;
}
__device__ __forceinline__ float bf2f(ushort_t h){ return __uint_as_float(((uint_t)h) << 16); }
__device__ __forceinline__ float bflo(uint_t u){ return __uint_as_float(u << 16); }
__device__ __forceinline__ float bfhi(uint_t u){ return __uint_as_float(u & 0xFFFF0000u); }
__device__ __forceinline__ float lrelu02(float u){ return fmaxf(u, 0.f) + 0.2f*fminf(u, 0.f); }
__device__ __forceinline__ float gelu_exact(float x){ return 0.5f*x*(1.f + erff(x*0.70710678118654752f)); }

// per-row LN stats over 17x128 fp32 tile (stride XS) -> sMU/sRS ; caller syncs
__device__ __forceinline__ void ln_stats(const float* sXp, float* sMU, float* sRS, int t){
    if (t < 136){
        int g = t >> 3, w = t & 7;
        const float4* row = (const float4*)(sXp + g*XS);
        float s = 0.f, q = 0.f;
        #pragma unroll
        for (int cc = 0; cc < 4; cc++){
            float4 v = row[w*4 + cc];
            s += v.x + v.y + v.z + v.w;
            q += v.x*v.x + v.y*v.y + v.z*v.z + v.w*v.w;
        }
        s += __shfl_xor(s, 1); s += __shfl_xor(s, 2); s += __shfl_xor(s, 4);
        q += __shfl_xor(q, 1); q += __shfl_xor(q, 2); q += __shfl_xor(q, 4);
        if (w == 0){
            float m = s * (1.f/128.f);
            float var = q * (1.f/128.f) - m*m;
            sMU[g] = m;
            sRS[g] = rsqrtf(var + 1e-5f);
        }
    }
}

// prep: WT[f][k] bf16 hi/lo (f: 0..255 w1-col, 256..511 w2-col, 512..639 vw-col) + bcat
__global__ void prep_kernel(const float* __restrict__ w1, const float* __restrict__ b1,
                            const float* __restrict__ w2, const float* __restrict__ b2,
                            const float* __restrict__ vw, const float* __restrict__ vb,
                            ushort_t* __restrict__ whi, ushort_t* __restrict__ wlo,
                            float* __restrict__ bcat){
    int gid = blockIdx.x*256 + threadIdx.x;
    if (gid < 640*128){
        int f = gid >> 7, k = gid & 127;
        float v;
        if (f < 256)      v = w1[k*256 + f];
        else if (f < 512) v = w2[k*256 + (f-256)];
        else              v = vw[k*128 + (f-512)];
        ushort_t h = f2bf(v);
        whi[gid] = h;
        wlo[gid] = f2bf(v - bf2f(h));
    }
    if (gid < 640){
        float b;
        if (gid < 256)      b = b1[gid];
        else if (gid < 512) b = b2[gid-256];
        else                b = vb[gid-512];
        bcat[gid] = b;
    }
}

__global__ __launch_bounds__(NTHREADS, 1)
void appnp_kernel(const float* __restrict__ x,
                  const float* __restrict__ og, const float* __restrict__ ob,
                  const float* __restrict__ lg, const float* __restrict__ lb,
                  const float* __restrict__ aw, const float* __restrict__ ab,
                  const float* __restrict__ psw, const float* __restrict__ psb,
                  const ushort_t* __restrict__ whi, const ushort_t* __restrict__ wlo,
                  const float* __restrict__ bcat,
                  float* __restrict__ out)
{
    __shared__ __align__(16) float smem[15430];   // 61,720 B < 64 KiB static limit
    float*    sX   = smem;                        // [0,2244)       fp32 state x
    float*    sV   = smem + 2248;                 // [2248,4492)    fp32 V
    ushort_t* sXh  = (ushort_t*)(smem + 4492);    // 17*136 ush     xn bf16-hi
    ushort_t* sXl  = (ushort_t*)(smem + 5648);    // 17*136 ush     xn bf16-lo
    ushort_t* sLb  = (ushort_t*)(smem + 6804);    // 17*264 ush     l bf16
    ushort_t* sRb  = (ushort_t*)(smem + 9048);    // 17*264 ush     r bf16
    float*    sX0  = smem + 11292;                // [11292,13536)  fp32 x0
    float*    sS   = smem + 13536;                // 680 (scores)
    float*    sMU  = smem + 14216;                // 20
    float*    sRS  = smem + 14236;                // 20
    float*    sK   = smem + 14256;                // 20
    float*    sLG  = smem + 14276;                // 128
    float*    sLBt = smem + 14404;                // 128
    float*    sPW  = smem + 14532;                // 128
    float*    sAW  = smem + 14660;                // 128
    float*    sBC  = smem + 14788;                // 642 (bcat + psb + ab)

    const int t = threadIdx.x;
    const int wave = t >> 6, lane = t & 63, l16 = lane & 15, quad = lane >> 4;
    const long long base = (long long)blockIdx.x * TOKE;

    // ---- weight preamble: wave's 80-feature strip (hi+lo) into registers ----
    short8 Wh[5][4], Wl[5][4];
    #pragma unroll
    for (int ft = 0; ft < 5; ft++){
        const ushort_t* ah = whi + (wave*80 + ft*16 + l16)*128 + quad*8;
        const ushort_t* al = wlo + (wave*80 + ft*16 + l16)*128 + quad*8;
        #pragma unroll
        for (int ks = 0; ks < 4; ks++){
            Wh[ft][ks] = *(const short8*)(ah + ks*32);
            Wl[ft][ks] = *(const short8*)(al + ks*32);
        }
    }

    // ---- stage small params into LDS ----
    if (t < 128){
        sLG[t]  = lg[t];
        sLBt[t] = lb[t];
        sPW[t]  = psw[t];
        sAW[t]  = aw[t];
    }
    for (int i = t; i < 640; i += NTHREADS) sBC[i] = bcat[i];
    if (t == 0){ sBC[640] = psb[0]; sBC[641] = ab[0]; }

    // ---- load x ----
    for (int idx = t; idx < TOKE; idx += NTHREADS){
        sX[(idx>>7)*XS + (idx&127)] = x[base + idx];
    }
    __syncthreads();

    // ---- outer LN -> sX (in place, fp32) and sX0 (fp32) ----
    ln_stats(sX, sMU, sRS, t);
    __syncthreads();
    for (int idx = t; idx < 544; idx += NTHREADS){
        int r = idx >> 5, c = (idx & 31) << 2;
        float mu = sMU[r], rs = sRS[r];
        float4 v = *(const float4*)(sX + r*XS + c);
        float4 g = *(const float4*)(og + c);
        float4 b = *(const float4*)(ob + c);
        v.x = (v.x-mu)*rs*g.x + b.x;  v.y = (v.y-mu)*rs*g.y + b.y;
        v.z = (v.z-mu)*rs*g.z + b.z;  v.w = (v.w-mu)*rs*g.w + b.w;
        *(float4*)(sX  + r*XS + c) = v;
        *(float4*)(sX0 + r*XS + c) = v;
    }
    __syncthreads();

    for (int it = 0; it < 4; it++){
        // ---- (a) inner LN: sX -> sXh/sXl (bf16 hi/lo), sX preserved ----
        ln_stats(sX, sMU, sRS, t);
        __syncthreads();
        for (int idx = t; idx < 544; idx += NTHREADS){
            int r = idx >> 5, c = (idx & 31) << 2;
            float mu = sMU[r], rs = sRS[r];
            float4 v = *(const float4*)(sX + r*XS + c);
            float4 g = *(const float4*)(sLG + c);
            float4 b = *(const float4*)(sLBt + c);
            float n0 = (v.x-mu)*rs*g.x + b.x, n1 = (v.y-mu)*rs*g.y + b.y;
            float n2 = (v.z-mu)*rs*g.z + b.z, n3 = (v.w-mu)*rs*g.w + b.w;
            ushort_t h0 = f2bf(n0), h1 = f2bf(n1), h2 = f2bf(n2), h3 = f2bf(n3);
            uint2 ph; ph.x = (uint_t)h0 | ((uint_t)h1 << 16); ph.y = (uint_t)h2 | ((uint_t)h3 << 16);
            ushort_t e0 = f2bf(n0 - bf2f(h0)), e1 = f2bf(n1 - bf2f(h1));
            ushort_t e2 = f2bf(n2 - bf2f(h2)), e3 = f2bf(n3 - bf2f(h3));
            uint2 pl; pl.x = (uint_t)e0 | ((uint_t)e1 << 16); pl.y = (uint_t)e2 | ((uint_t)e3 << 16);
            *(uint2*)(sXh + r*XBS + c) = ph;
            *(uint2*)(sXl + r*XBS + c) = pl;
        }
        __syncthreads();

        // ---- (b) MFMA GEMM: D(640 x 17) = W(regs, bf16 hi/lo) @ xn^T(hi+lo) ----
        #pragma unroll
        for (int nt = 0; nt < 2; nt++){
            int rbase = nt*16 + l16;
            // cols >= NJ read a valid junk row (their D columns are discarded)
            int rr = (rbase < NJ) ? rbase : (rbase - 16);
            const ushort_t* bhp = sXh + rr*XBS + quad*8;
            const ushort_t* blp = sXl + rr*XBS + quad*8;
            short8 Bh[4], Bl[4];
            #pragma unroll
            for (int ks = 0; ks < 4; ks++){
                Bh[ks] = *(const short8*)(bhp + ks*32);
                Bl[ks] = *(const short8*)(blp + ks*32);
            }
            #pragma unroll
            for (int ft = 0; ft < 5; ft++){
                int f0 = wave*80 + ft*16;
                float4 bb = *(const float4*)(sBC + f0 + quad*4);
                f32x4 acc; acc[0] = bb.x; acc[1] = bb.y; acc[2] = bb.z; acc[3] = bb.w;
                #pragma unroll
                for (int ks = 0; ks < 4; ks++){
                    acc = __builtin_amdgcn_mfma_f32_16x16x32_bf16(Wh[ft][ks], Bh[ks], acc, 0, 0, 0);
                    acc = __builtin_amdgcn_mfma_f32_16x16x32_bf16(Wh[ft][ks], Bl[ks], acc, 0, 0, 0);
                    acc = __builtin_amdgcn_mfma_f32_16x16x32_bf16(Wl[ft][ks], Bh[ks], acc, 0, 0, 0);
                }
                if (rbase < NJ){
                    int fb = f0 + quad*4;
                    if (f0 < 512){
                        ushort_t* dst = (f0 < 256) ? (sLb + rbase*LBS + fb) : (sRb + rbase*LBS + (fb - 256));
                        uint2 p;
                        p.x = (uint_t)f2bf(acc[0]) | ((uint_t)f2bf(acc[1]) << 16);
                        p.y = (uint_t)f2bf(acc[2]) | ((uint_t)f2bf(acc[3]) << 16);
                        *(uint2*)dst = p;
                    } else {
                        float4 o; o.x = acc[0]; o.y = acc[1]; o.z = acc[2]; o.w = acc[3];
                        *(float4*)(sV + rbase*XS + (fb - 512)) = o;
                    }
                }
            }
        }
        __syncthreads();

        // ---- (c) attention scores (t<98) + skip gate (t 98..114) ----
        if (t < 98){
            int h = (t >= 49);
            int p = t - 49*h;
            unsigned short pr = PAIR[p];
            int i = pr >> 8, j = pr & 255;
            const uint4* lp = (const uint4*)(sLb + i*LBS + h*128);
            const uint4* rp = (const uint4*)(sRb + j*LBS + h*128);
            float acc = 0.f;
            #pragma unroll
            for (int d = 0; d < 16; d++){
                uint4 lu = lp[d], ru = rp[d];
                float4 p0 = *(const float4*)(sPW + d*8);
                float4 p1 = *(const float4*)(sPW + d*8 + 4);
                acc += lrelu02(bflo(lu.x) + bflo(ru.x)) * p0.x;
                acc += lrelu02(bfhi(lu.x) + bfhi(ru.x)) * p0.y;
                acc += lrelu02(bflo(lu.y) + bflo(ru.y)) * p0.z;
                acc += lrelu02(bfhi(lu.y) + bfhi(ru.y)) * p0.w;
                acc += lrelu02(bflo(lu.z) + bflo(ru.z)) * p1.x;
                acc += lrelu02(bfhi(lu.z) + bfhi(ru.z)) * p1.y;
                acc += lrelu02(bflo(lu.w) + bflo(ru.w)) * p1.z;
                acc += lrelu02(bfhi(lu.w) + bfhi(ru.w)) * p1.w;
            }
            sS[(h*NJ + i)*SS + j] = acc + sBC[640];
        } else if (t < 115){
            int i = t - 98;
            const uint4* xh = (const uint4*)(sXh + i*XBS);
            const uint4* xl = (const uint4*)(sXl + i*XBS);
            float acc = 0.f;
            #pragma unroll
            for (int d = 0; d < 16; d++){
                uint4 uh = xh[d], ul = xl[d];
                float4 a0 = *(const float4*)(sAW + d*8);
                float4 a1 = *(const float4*)(sAW + d*8 + 4);
                acc += (bflo(uh.x) + bflo(ul.x)) * a0.x;
                acc += (bfhi(uh.x) + bfhi(ul.x)) * a0.y;
                acc += (bflo(uh.y) + bflo(ul.y)) * a0.z;
                acc += (bfhi(uh.y) + bfhi(ul.y)) * a0.w;
                acc += (bflo(uh.z) + bflo(ul.z)) * a1.x;
                acc += (bfhi(uh.z) + bfhi(ul.z)) * a1.y;
                acc += (bflo(uh.w) + bflo(ul.w)) * a1.z;
                acc += (bfhi(uh.w) + bfhi(ul.w)) * a1.w;
            }
            sK[i] = 1.f / (1.f + expf(-(acc + sBC[641])));
        }
        __syncthreads();

        // ---- (d) masked softmax (t<34) ----
        if (t < 34){
            int h = (t >= NJ);
            int i = t - h*NJ;
            float* sp = sS + (h*NJ + i)*SS;
            unsigned int m = ADJM[i];
            float mx = -1e30f;
            #pragma unroll
            for (int j = 0; j < NJ; j++) if ((m >> j) & 1u) mx = fmaxf(mx, sp[j]);
            float pv[NJ]; float sum = 0.f;
            #pragma unroll
            for (int j = 0; j < NJ; j++){
                if ((m >> j) & 1u){ pv[j] = expf(sp[j] - mx); sum += pv[j]; }
                else pv[j] = 0.f;
            }
            float inv = 1.f / sum;
            #pragma unroll
            for (int j = 0; j < NJ; j++) sp[j] = pv[j]*inv;
        }
        __syncthreads();

        // ---- (e) PV + gelu + blend (x0 fp32) -> new x in sX ----
        for (int idx = t; idx < 544; idx += NTHREADS){
            int r = idx >> 5, cg = idx & 31;
            int c = cg << 2, h = cg >> 4;
            const float* sp = sS + (h*NJ + r)*SS;
            float a0 = 0.f, a1 = 0.f, a2 = 0.f, a3 = 0.f;
            #pragma unroll
            for (int j = 0; j < NJ; j++){
                float pj = sp[j];
                float4 vv = *(const float4*)(sV + j*XS + c);
                a0 += pj*vv.x; a1 += pj*vv.y; a2 += pj*vv.z; a3 += pj*vv.w;
            }
            a0 = gelu_exact(a0); a1 = gelu_exact(a1); a2 = gelu_exact(a2); a3 = gelu_exact(a3);
            float sk = sK[r];
            float4 x0v = *(const float4*)(sX0 + r*XS + c);
            float4 nx;
            nx.x = (1.f-sk)*a0 + sk*x0v.x;  nx.y = (1.f-sk)*a1 + sk*x0v.y;
            nx.z = (1.f-sk)*a2 + sk*x0v.z;  nx.w = (1.f-sk)*a3 + sk*x0v.w;
            *(float4*)(sX + r*XS + c) = nx;
        }
        __syncthreads();
    }

    // ---- store ----
    for (int idx = t; idx < TOKE; idx += NTHREADS){
        out[base + idx] = sX[(idx>>7)*XS + (idx&127)];
    }
}

extern "C" void kernel_launch(void* const* d_in, const int* in_sizes, int n_in,
                              void* d_out, int out_size, void* d_ws, size_t ws_size,
                              hipStream_t stream) {
    const float* x   = (const float*)d_in[0];
    const float* og  = (const float*)d_in[1];
    const float* ob  = (const float*)d_in[2];
    const float* lg  = (const float*)d_in[3];
    const float* lb  = (const float*)d_in[4];
    const float* aw  = (const float*)d_in[5];
    const float* ab  = (const float*)d_in[6];
    const float* w1  = (const float*)d_in[7];
    const float* b1  = (const float*)d_in[8];
    const float* w2  = (const float*)d_in[9];
    const float* b2  = (const float*)d_in[10];
    const float* psw = (const float*)d_in[11];
    const float* psb = (const float*)d_in[12];
    const float* vw  = (const float*)d_in[13];
    const float* vb  = (const float*)d_in[14];
    float* out = (float*)d_out;

    // workspace: whi (640*128 bf16) + wlo (640*128 bf16) + bcat (640 f32) = 330,240 B
    ushort_t* whi = (ushort_t*)d_ws;
    ushort_t* wlo = whi + 640*128;
    float* bcat = (float*)(wlo + 640*128);

    prep_kernel<<<dim3(320), dim3(256), 0, stream>>>(w1, b1, w2, b2, vw, vb, whi, wlo, bcat);

    int BT = in_sizes[0] / TOKE;   // 3888 tokens
    appnp_kernel<<<dim3(BT), dim3(NTHREADS), 0, stream>>>(
        x, og, ob, lg, lb, aw, ab, psw, psb, whi, wlo, bcat, out);
}

// Round 7
// 1040.885 us; speedup vs baseline: 1.4089x; 1.0512x over previous
//
#include <hip/hip_runtime.h>
#include <math.h>

#define NJ 17
#define DD 128
#define XS 132      // fp32 row stride for sX/sV/sX0 (floats)
#define LBS 264     // ushort row stride for sLb/sRb (bf16)
#define XBS 136     // ushort row stride for sXh/sXl (bf16)
#define SS 20       // score row stride
#define TOKE (NJ*DD)
#define NTHREADS 512

typedef unsigned short ushort_t;
typedef unsigned int uint_t;
typedef __attribute__((ext_vector_type(8))) short short8;
typedef __attribute__((ext_vector_type(4))) float f32x4;

// adjacency bitmasks (both dirs + diag)
__device__ __constant__ unsigned int ADJM[NJ] = {
    0x93u, 0x7u, 0xEu, 0xCu, 0x31u, 0x70u, 0x60u,
    0x181u, 0x4B80u, 0x700u, 0x600u, 0x1900u, 0x3800u, 0x3000u,
    0xC100u, 0x1C000u, 0x18000u
};
// dense list of the 49 adjacent (i,j) pairs, packed (i<<8)|j
__device__ __constant__ unsigned short PAIR[49] = {
    0x0000,0x0001,0x0004,0x0007, 0x0100,0x0101,0x0102, 0x0201,0x0202,0x0203,
    0x0302,0x0303, 0x0400,0x0404,0x0405, 0x0504,0x0505,0x0506, 0x0605,0x0606,
    0x0700,0x0707,0x0708, 0x0807,0x0808,0x0809,0x080B,0x080E, 0x0908,0x0909,0x090A,
    0x0A09,0x0A0A, 0x0B08,0x0B0B,0x0B0C, 0x0C0B,0x0C0C,0x0C0D, 0x0D0C,0x0D0D,
    0x0E08,0x0E0E,0x0E0F, 0x0F0E,0x0F0F,0x0F10, 0x100F,0x1010
};

__device__ __forceinline__ ushort_t f2bf(float v){
    uint_t u = __float_as_uint(v);
    uint_t r = (u + 0x7FFFu + ((u >> 16) & 1u)) >> 16;
    return (ushort_t)r;
}
__device__ __forceinline__ float bf2f(ushort_t h){ return __uint_as_float(((uint_t)h) << 16); }
__device__ __forceinline__ float bflo(uint_t u){ return __uint_as_float(u << 16); }
__device__ __forceinline__ float bfhi(uint_t u){ return __uint_as_float(u & 0xFFFF0000u); }
__device__ __forceinline__ float lrelu02(float u){ return fmaxf(u, 0.f) + 0.2f*fminf(u, 0.f); }
__device__ __forceinline__ float gelu_exact(float x){ return 0.5f*x*(1.f + erff(x*0.70710678118654752f)); }

// per-row LN stats over 17x128 fp32 tile (stride XS) -> sMU/sRS ; caller syncs
__device__ __forceinline__ void ln_stats(const float* sXp, float* sMU, float* sRS, int t){
    if (t < 136){
        int g = t >> 3, w = t & 7;
        const float4* row = (const float4*)(sXp + g*XS);
        float s = 0.f, q = 0.f;
        #pragma unroll
        for (int cc = 0; cc < 4; cc++){
            float4 v = row[w*4 + cc];
            s += v.x + v.y + v.z + v.w;
            q += v.x*v.x + v.y*v.y + v.z*v.z + v.w*v.w;
        }
        s += __shfl_xor(s, 1); s += __shfl_xor(s, 2); s += __shfl_xor(s, 4);
        q += __shfl_xor(q, 1); q += __shfl_xor(q, 2); q += __shfl_xor(q, 4);
        if (w == 0){
            float m = s * (1.f/128.f);
            float var = q * (1.f/128.f) - m*m;
            sMU[g] = m;
            sRS[g] = rsqrtf(var + 1e-5f);
        }
    }
}

// prep: WT[f][k] bf16 hi/lo (f: 0..255 w1-col, 256..511 w2-col, 512..639 vw-col) + bcat
__global__ void prep_kernel(const float* __restrict__ w1, const float* __restrict__ b1,
                            const float* __restrict__ w2, const float* __restrict__ b2,
                            const float* __restrict__ vw, const float* __restrict__ vb,
                            ushort_t* __restrict__ whi, ushort_t* __restrict__ wlo,
                            float* __restrict__ bcat){
    int gid = blockIdx.x*256 + threadIdx.x;
    if (gid < 640*128){
        int f = gid >> 7, k = gid & 127;
        float v;
        if (f < 256)      v = w1[k*256 + f];
        else if (f < 512) v = w2[k*256 + (f-256)];
        else              v = vw[k*128 + (f-512)];
        ushort_t h = f2bf(v);
        whi[gid] = h;
        wlo[gid] = f2bf(v - bf2f(h));
    }
    if (gid < 640){
        float b;
        if (gid < 256)      b = b1[gid];
        else if (gid < 512) b = b2[gid-256];
        else                b = vb[gid-512];
        bcat[gid] = b;
    }
}

// pin exact occupancy: 2 waves/EU -> full 256-reg/wave budget visible to RA
__attribute__((amdgpu_flat_work_group_size(NTHREADS, NTHREADS), amdgpu_waves_per_eu(2, 2)))
__global__ void appnp_kernel(const float* __restrict__ x,
                  const float* __restrict__ og, const float* __restrict__ ob,
                  const float* __restrict__ lg, const float* __restrict__ lb,
                  const float* __restrict__ aw, const float* __restrict__ ab,
                  const float* __restrict__ psw, const float* __restrict__ psb,
                  const ushort_t* __restrict__ whi, const ushort_t* __restrict__ wlo,
                  const float* __restrict__ bcat,
                  float* __restrict__ out)
{
    __shared__ __align__(16) float smem[15430];   // 61,720 B < 64 KiB static limit
    float*    sX   = smem;                        // [0,2244)       fp32 state x
    float*    sV   = smem + 2248;                 // [2248,4492)    fp32 V
    ushort_t* sXh  = (ushort_t*)(smem + 4492);    // 17*136 ush     xn bf16-hi
    ushort_t* sXl  = (ushort_t*)(smem + 5648);    // 17*136 ush     xn bf16-lo
    ushort_t* sLb  = (ushort_t*)(smem + 6804);    // 17*264 ush     l bf16
    ushort_t* sRb  = (ushort_t*)(smem + 9048);    // 17*264 ush     r bf16
    float*    sX0  = smem + 11292;                // [11292,13536)  fp32 x0
    float*    sS   = smem + 13536;                // 680 (scores)
    float*    sMU  = smem + 14216;                // 20
    float*    sRS  = smem + 14236;                // 20
    float*    sK   = smem + 14256;                // 20
    float*    sLG  = smem + 14276;                // 128
    float*    sLBt = smem + 14404;                // 128
    float*    sPW  = smem + 14532;                // 128
    float*    sAW  = smem + 14660;                // 128
    float*    sBC  = smem + 14788;                // 642 (bcat + psb + ab)

    const int t = threadIdx.x;
    const int wave = t >> 6, lane = t & 63, l16 = lane & 15, quad = lane >> 4;
    const long long base = (long long)blockIdx.x * TOKE;

    // ---- weight preamble: wave's 80-feature strip (hi+lo) into registers ----
    short8 Wh[5][4], Wl[5][4];
    #pragma unroll
    for (int ft = 0; ft < 5; ft++){
        const ushort_t* ah = whi + (wave*80 + ft*16 + l16)*128 + quad*8;
        const ushort_t* al = wlo + (wave*80 + ft*16 + l16)*128 + quad*8;
        #pragma unroll
        for (int ks = 0; ks < 4; ks++){
            Wh[ft][ks] = *(const short8*)(ah + ks*32);
            Wl[ft][ks] = *(const short8*)(al + ks*32);
        }
    }

    // ---- stage small params into LDS ----
    if (t < 128){
        sLG[t]  = lg[t];
        sLBt[t] = lb[t];
        sPW[t]  = psw[t];
        sAW[t]  = aw[t];
    }
    for (int i = t; i < 640; i += NTHREADS) sBC[i] = bcat[i];
    if (t == 0){ sBC[640] = psb[0]; sBC[641] = ab[0]; }

    // ---- load x ----
    for (int idx = t; idx < TOKE; idx += NTHREADS){
        sX[(idx>>7)*XS + (idx&127)] = x[base + idx];
    }
    __syncthreads();

    // ---- outer LN -> sX (in place, fp32) and sX0 (fp32) ----
    ln_stats(sX, sMU, sRS, t);
    __syncthreads();
    for (int idx = t; idx < 544; idx += NTHREADS){
        int r = idx >> 5, c = (idx & 31) << 2;
        float mu = sMU[r], rs = sRS[r];
        float4 v = *(const float4*)(sX + r*XS + c);
        float4 g = *(const float4*)(og + c);
        float4 b = *(const float4*)(ob + c);
        v.x = (v.x-mu)*rs*g.x + b.x;  v.y = (v.y-mu)*rs*g.y + b.y;
        v.z = (v.z-mu)*rs*g.z + b.z;  v.w = (v.w-mu)*rs*g.w + b.w;
        *(float4*)(sX  + r*XS + c) = v;
        *(float4*)(sX0 + r*XS + c) = v;
    }
    __syncthreads();

    for (int it = 0; it < 4; it++){
        // ---- (a) inner LN: sX -> sXh/sXl (bf16 hi/lo), sX preserved ----
        ln_stats(sX, sMU, sRS, t);
        __syncthreads();
        for (int idx = t; idx < 544; idx += NTHREADS){
            int r = idx >> 5, c = (idx & 31) << 2;
            float mu = sMU[r], rs = sRS[r];
            float4 v = *(const float4*)(sX + r*XS + c);
            float4 g = *(const float4*)(sLG + c);
            float4 b = *(const float4*)(sLBt + c);
            float n0 = (v.x-mu)*rs*g.x + b.x, n1 = (v.y-mu)*rs*g.y + b.y;
            float n2 = (v.z-mu)*rs*g.z + b.z, n3 = (v.w-mu)*rs*g.w + b.w;
            ushort_t h0 = f2bf(n0), h1 = f2bf(n1), h2 = f2bf(n2), h3 = f2bf(n3);
            uint2 ph; ph.x = (uint_t)h0 | ((uint_t)h1 << 16); ph.y = (uint_t)h2 | ((uint_t)h3 << 16);
            ushort_t e0 = f2bf(n0 - bf2f(h0)), e1 = f2bf(n1 - bf2f(h1));
            ushort_t e2 = f2bf(n2 - bf2f(h2)), e3 = f2bf(n3 - bf2f(h3));
            uint2 pl; pl.x = (uint_t)e0 | ((uint_t)e1 << 16); pl.y = (uint_t)e2 | ((uint_t)e3 << 16);
            *(uint2*)(sXh + r*XBS + c) = ph;
            *(uint2*)(sXl + r*XBS + c) = pl;
        }
        __syncthreads();

        // ---- (b) MFMA GEMM: D(640 x 17) = W(regs, bf16 hi/lo) @ xn^T(hi+lo) ----
        // nt NOT unrolled: only one nt's B-frags live at a time (register budget)
        #pragma unroll 1
        for (int nt = 0; nt < 2; nt++){
            int rbase = nt*16 + l16;
            // cols >= NJ read a valid junk row (their D columns are discarded)
            int rr = (rbase < NJ) ? rbase : (rbase - 16);
            const ushort_t* bhp = sXh + rr*XBS + quad*8;
            const ushort_t* blp = sXl + rr*XBS + quad*8;
            short8 Bh[4], Bl[4];
            #pragma unroll
            for (int ks = 0; ks < 4; ks++){
                Bh[ks] = *(const short8*)(bhp + ks*32);
                Bl[ks] = *(const short8*)(blp + ks*32);
            }
            #pragma unroll 2
            for (int ft = 0; ft < 5; ft++){
                int f0 = wave*80 + ft*16;
                float4 bb = *(const float4*)(sBC + f0 + quad*4);
                f32x4 acc; acc[0] = bb.x; acc[1] = bb.y; acc[2] = bb.z; acc[3] = bb.w;
                #pragma unroll
                for (int ks = 0; ks < 4; ks++){
                    acc = __builtin_amdgcn_mfma_f32_16x16x32_bf16(Wh[ft][ks], Bh[ks], acc, 0, 0, 0);
                    acc = __builtin_amdgcn_mfma_f32_16x16x32_bf16(Wh[ft][ks], Bl[ks], acc, 0, 0, 0);
                    acc = __builtin_amdgcn_mfma_f32_16x16x32_bf16(Wl[ft][ks], Bh[ks], acc, 0, 0, 0);
                }
                if (rbase < NJ){
                    int fb = f0 + quad*4;
                    if (f0 < 512){
                        ushort_t* dst = (f0 < 256) ? (sLb + rbase*LBS + fb) : (sRb + rbase*LBS + (fb - 256));
                        uint2 p;
                        p.x = (uint_t)f2bf(acc[0]) | ((uint_t)f2bf(acc[1]) << 16);
                        p.y = (uint_t)f2bf(acc[2]) | ((uint_t)f2bf(acc[3]) << 16);
                        *(uint2*)dst = p;
                    } else {
                        float4 o; o.x = acc[0]; o.y = acc[1]; o.z = acc[2]; o.w = acc[3];
                        *(float4*)(sV + rbase*XS + (fb - 512)) = o;
                    }
                }
            }
        }
        __syncthreads();

        // ---- (c) attention scores (t<98) + skip gate (t 98..114) ----
        if (t < 98){
            int h = (t >= 49);
            int p = t - 49*h;
            unsigned short pr = PAIR[p];
            int i = pr >> 8, j = pr & 255;
            const uint4* lp = (const uint4*)(sLb + i*LBS + h*128);
            const uint4* rp = (const uint4*)(sRb + j*LBS + h*128);
            float acc = 0.f;
            #pragma unroll
            for (int d = 0; d < 16; d++){
                uint4 lu = lp[d], ru = rp[d];
                float4 p0 = *(const float4*)(sPW + d*8);
                float4 p1 = *(const float4*)(sPW + d*8 + 4);
                acc += lrelu02(bflo(lu.x) + bflo(ru.x)) * p0.x;
                acc += lrelu02(bfhi(lu.x) + bfhi(ru.x)) * p0.y;
                acc += lrelu02(bflo(lu.y) + bflo(ru.y)) * p0.z;
                acc += lrelu02(bfhi(lu.y) + bfhi(ru.y)) * p0.w;
                acc += lrelu02(bflo(lu.z) + bflo(ru.z)) * p1.x;
                acc += lrelu02(bfhi(lu.z) + bfhi(ru.z)) * p1.y;
                acc += lrelu02(bflo(lu.w) + bflo(ru.w)) * p1.z;
                acc += lrelu02(bfhi(lu.w) + bfhi(ru.w)) * p1.w;
            }
            sS[(h*NJ + i)*SS + j] = acc + sBC[640];
        } else if (t < 115){
            int i = t - 98;
            const uint4* xh = (const uint4*)(sXh + i*XBS);
            const uint4* xl = (const uint4*)(sXl + i*XBS);
            float acc = 0.f;
            #pragma unroll
            for (int d = 0; d < 16; d++){
                uint4 uh = xh[d], ul = xl[d];
                float4 a0 = *(const float4*)(sAW + d*8);
                float4 a1 = *(const float4*)(sAW + d*8 + 4);
                acc += (bflo(uh.x) + bflo(ul.x)) * a0.x;
                acc += (bfhi(uh.x) + bfhi(ul.x)) * a0.y;
                acc += (bflo(uh.y) + bflo(ul.y)) * a0.z;
                acc += (bfhi(uh.y) + bfhi(ul.y)) * a0.w;
                acc += (bflo(uh.z) + bflo(ul.z)) * a1.x;
                acc += (bfhi(uh.z) + bfhi(ul.z)) * a1.y;
                acc += (bflo(uh.w) + bflo(ul.w)) * a1.z;
                acc += (bfhi(uh.w) + bfhi(ul.w)) * a1.w;
            }
            sK[i] = 1.f / (1.f + expf(-(acc + sBC[641])));
        }
        __syncthreads();

        // ---- (d) masked softmax (t<34) ----
        if (t < 34){
            int h = (t >= NJ);
            int i = t - h*NJ;
            float* sp = sS + (h*NJ + i)*SS;
            unsigned int m = ADJM[i];
            float mx = -1e30f;
            #pragma unroll
            for (int j = 0; j < NJ; j++) if ((m >> j) & 1u) mx = fmaxf(mx, sp[j]);
            float pv[NJ]; float sum = 0.f;
            #pragma unroll
            for (int j = 0; j < NJ; j++){
                if ((m >> j) & 1u){ pv[j] = expf(sp[j] - mx); sum += pv[j]; }
                else pv[j] = 0.f;
            }
            float inv = 1.f / sum;
            #pragma unroll
            for (int j = 0; j < NJ; j++) sp[j] = pv[j]*inv;
        }
        __syncthreads();

        // ---- (e) PV + gelu + blend (x0 fp32) -> new x in sX ----
        for (int idx = t; idx < 544; idx += NTHREADS){
            int r = idx >> 5, cg = idx & 31;
            int c = cg << 2, h = cg >> 4;
            const float* sp = sS + (h*NJ + r)*SS;
            float a0 = 0.f, a1 = 0.f, a2 = 0.f, a3 = 0.f;
            #pragma unroll
            for (int j = 0; j < NJ; j++){
                float pj = sp[j];
                float4 vv = *(const float4*)(sV + j*XS + c);
                a0 += pj*vv.x; a1 += pj*vv.y; a2 += pj*vv.z; a3 += pj*vv.w;
            }
            a0 = gelu_exact(a0); a1 = gelu_exact(a1); a2 = gelu_exact(a2); a3 = gelu_exact(a3);
            float sk = sK[r];
            float4 x0v = *(const float4*)(sX0 + r*XS + c);
            float4 nx;
            nx.x = (1.f-sk)*a0 + sk*x0v.x;  nx.y = (1.f-sk)*a1 + sk*x0v.y;
            nx.z = (1.f-sk)*a2 + sk*x0v.z;  nx.w = (1.f-sk)*a3 + sk*x0v.w;
            *(float4*)(sX + r*XS + c) = nx;
        }
        __syncthreads();
    }

    // ---- store ----
    for (int idx = t; idx < TOKE; idx += NTHREADS){
        out[base + idx] = sX[(idx>>7)*XS + (idx&127)];
    }
}

extern "C" void kernel_launch(void* const* d_in, const int* in_sizes, int n_in,
                              void* d_out, int out_size, void* d_ws, size_t ws_size,
                              hipStream_t stream) {
    const float* x   = (const float*)d_in[0];
    const float* og  = (const float*)d_in[1];
    const float* ob  = (const float*)d_in[2];
    const float* lg  = (const float*)d_in[3];
    const float* lb  = (const float*)d_in[4];
    const float* aw  = (const float*)d_in[5];
    const float* ab  = (const float*)d_in[6];
    const float* w1  = (const float*)d_in[7];
    const float* b1  = (const float*)d_in[8];
    const float* w2  = (const float*)d_in[9];
    const float* b2  = (const float*)d_in[10];
    const float* psw = (const float*)d_in[11];
    const float* psb = (const float*)d_in[12];
    const float* vw  = (const float*)d_in[13];
    const float* vb  = (const float*)d_in[14];
    float* out = (float*)d_out;

    // workspace: whi (640*128 bf16) + wlo (640*128 bf16) + bcat (640 f32) = 330,240 B
    ushort_t* whi = (ushort_t*)d_ws;
    ushort_t* wlo = whi + 640*128;
    float* bcat = (float*)(wlo + 640*128);

    prep_kernel<<<dim3(320), dim3(256), 0, stream>>>(w1, b1, w2, b2, vw, vb, whi, wlo, bcat);

    int BT = in_sizes[0] / TOKE;   // 3888 tokens
    appnp_kernel<<<dim3(BT), dim3(NTHREADS), 0, stream>>>(
        x, og, ob, lg, lb, aw, ab, psw, psb, whi, wlo, bcat, out);
}

// Round 8
// 787.372 us; speedup vs baseline: 1.8625x; 1.3220x over previous
//
#include <hip/hip_runtime.h>
#include <math.h>

#define NJ 17
#define DD 128
#define XS 132      // fp32 row stride for sX/sV (floats)
#define LBS 264     // ushort row stride for sLb/sRb (bf16)
#define XBS 136     // ushort row stride for sXh/sXl (bf16)
#define SS 20       // score row stride
#define TOKE (NJ*DD)

typedef unsigned short ushort_t;
typedef unsigned int uint_t;
typedef __attribute__((ext_vector_type(8))) short short8;
typedef __attribute__((ext_vector_type(4))) float f32x4;

// adjacency bitmasks (both dirs + diag)
__device__ __constant__ unsigned int ADJM[NJ] = {
    0x93u, 0x7u, 0xEu, 0xCu, 0x31u, 0x70u, 0x60u,
    0x181u, 0x4B80u, 0x700u, 0x600u, 0x1900u, 0x3800u, 0x3000u,
    0xC100u, 0x1C000u, 0x18000u
};
// dense list of the 49 adjacent (i,j) pairs, packed (i<<8)|j
__device__ __constant__ unsigned short PAIR[49] = {
    0x0000,0x0001,0x0004,0x0007, 0x0100,0x0101,0x0102, 0x0201,0x0202,0x0203,
    0x0302,0x0303, 0x0400,0x0404,0x0405, 0x0504,0x0505,0x0506, 0x0605,0x0606,
    0x0700,0x0707,0x0708, 0x0807,0x0808,0x0809,0x080B,0x080E, 0x0908,0x0909,0x090A,
    0x0A09,0x0A0A, 0x0B08,0x0B0B,0x0B0C, 0x0C0B,0x0C0C,0x0C0D, 0x0D0C,0x0D0D,
    0x0E08,0x0E0E,0x0E0F, 0x0F0E,0x0F0F,0x0F10, 0x100F,0x1010
};

__device__ __forceinline__ uint_t f2bf(float v){
    uint_t u = __float_as_uint(v);
    return (u + 0x7FFFu + ((u >> 16) & 1u)) >> 16;
}
__device__ __forceinline__ float bf2f(uint_t h){ return __uint_as_float(h << 16); }
__device__ __forceinline__ float bflo(uint_t u){ return __uint_as_float(u << 16); }
__device__ __forceinline__ float bfhi(uint_t u){ return __uint_as_float(u & 0xFFFF0000u); }
__device__ __forceinline__ float lrelu02(float u){ return fmaxf(u, 0.f) + 0.2f*fminf(u, 0.f); }
__device__ __forceinline__ float gelu_exact(float x){ return 0.5f*x*(1.f + erff(x*0.70710678118654752f)); }

// prep: WT[f][k] bf16 hi/lo (f: 0..255 w1-col, 256..511 w2-col, 512..639 vw-col) + bcat
__global__ void prep_kernel(const float* __restrict__ w1, const float* __restrict__ b1,
                            const float* __restrict__ w2, const float* __restrict__ b2,
                            const float* __restrict__ vw, const float* __restrict__ vb,
                            ushort_t* __restrict__ whi, ushort_t* __restrict__ wlo,
                            float* __restrict__ bcat){
    int gid = blockIdx.x*256 + threadIdx.x;
    if (gid < 640*128){
        int f = gid >> 7, k = gid & 127;
        float v;
        if (f < 256)      v = w1[k*256 + f];
        else if (f < 512) v = w2[k*256 + (f-256)];
        else              v = vw[k*128 + (f-512)];
        uint_t h = f2bf(v);
        whi[gid] = (ushort_t)h;
        wlo[gid] = (ushort_t)f2bf(v - bf2f(h));
    }
    if (gid < 640){
        float b;
        if (gid < 256)      b = b1[gid];
        else if (gid < 512) b = b2[gid-256];
        else                b = vb[gid-512];
        bcat[gid] = b;
    }
}

__attribute__((amdgpu_flat_work_group_size(256, 256)))
__global__ void appnp_kernel(const float* __restrict__ x,
                  const float* __restrict__ og, const float* __restrict__ ob,
                  const float* __restrict__ lg, const float* __restrict__ lb,
                  const float* __restrict__ aw, const float* __restrict__ ab,
                  const float* __restrict__ psw, const float* __restrict__ psb,
                  const ushort_t* __restrict__ whi, const ushort_t* __restrict__ wlo,
                  const float* __restrict__ bcat,
                  float* __restrict__ out)
{
    __shared__ __align__(16) float smem[12466];   // 49,864 B -> 3 blocks/CU (149.6 KiB <= 160)
    float*    sX   = smem;                        // [0,2244)      fp32 state x
    float*    sV   = smem + 2248;                 // [2248,4492)   fp32 V
    ushort_t* sLb  = (ushort_t*)(smem + 4492);    // 17*264 ush    l bf16
    ushort_t* sRb  = (ushort_t*)(smem + 6736);    // 17*264 ush    r bf16
    ushort_t* sXh  = (ushort_t*)(smem + 8980);    // 17*136 ush    xn bf16-hi
    ushort_t* sXl  = (ushort_t*)(smem + 10136);   // 17*136 ush    xn bf16-lo
    float*    sS   = smem + 8980;                 // 680 f scores -- ALIASES sXh (dead after (b))
    float*    sK   = smem + 11292;                // 20
    float*    sLG  = smem + 11312;                // 128
    float*    sLBt = smem + 11440;                // 128
    float*    sPW  = smem + 11568;                // 128
    float*    sAW  = smem + 11696;                // 128
    float*    sBC  = smem + 11824;                // 642 (bcat + psb + ab)

    const int t = threadIdx.x;
    const int wave = t >> 6, lane = t & 63, l16 = lane & 15, quad = lane >> 4;
    const long long base = (long long)blockIdx.x * TOKE;

    // ---- stage small params ----
    if (t < 128){ sLG[t] = lg[t]; sLBt[t] = lb[t]; sPW[t] = psw[t]; sAW[t] = aw[t]; }
    for (int i = t; i < 642; i += 256)
        sBC[i] = (i < 640) ? bcat[i] : (i == 640 ? psb[0] : ab[0]);

    // ---- load x (544 float4 groups) ----
    for (int idx = t; idx < 544; idx += 256)
        *(float4*)(sX + (idx>>5)*XS + ((idx&31)<<2)) = *(const float4*)(x + base + idx*4);
    __syncthreads();

    // ---- outer LN (shfl stats over 32 threads/row) -> sX in place; x0 kept in regs ----
    float4 x0r[3];
    #pragma unroll
    for (int p = 0; p < 3; p++){
        int idx = t + (p << 8);
        if (p < 2 || t < 32){
            int r = idx >> 5, c = (idx & 31) << 2;
            float4 v = *(const float4*)(sX + r*XS + c);
            float s = v.x + v.y + v.z + v.w;
            float q = v.x*v.x + v.y*v.y + v.z*v.z + v.w*v.w;
            #pragma unroll
            for (int m = 1; m <= 16; m <<= 1){ s += __shfl_xor(s, m); q += __shfl_xor(q, m); }
            float mu = s * (1.f/128.f);
            float rs = rsqrtf(q * (1.f/128.f) - mu*mu + 1e-5f);
            float4 g = *(const float4*)(og + c);
            float4 b = *(const float4*)(ob + c);
            float4 nv;
            nv.x = (v.x-mu)*rs*g.x + b.x;  nv.y = (v.y-mu)*rs*g.y + b.y;
            nv.z = (v.z-mu)*rs*g.z + b.z;  nv.w = (v.w-mu)*rs*g.w + b.w;
            *(float4*)(sX + r*XS + c) = nv;
            x0r[p] = nv;
        }
    }
    __syncthreads();

    for (int it = 0; it < 4; it++){
        // ---- (a) inner LN -> sXh/sXl (bf16 hi/lo) + fused skip gate ----
        {
            const float abv = sBC[641];
            #pragma unroll
            for (int p = 0; p < 3; p++){
                int idx = t + (p << 8);
                if (p < 2 || t < 32){
                    int r = idx >> 5, c = (idx & 31) << 2;
                    float4 v = *(const float4*)(sX + r*XS + c);
                    float s = v.x + v.y + v.z + v.w;
                    float q = v.x*v.x + v.y*v.y + v.z*v.z + v.w*v.w;
                    #pragma unroll
                    for (int m = 1; m <= 16; m <<= 1){ s += __shfl_xor(s, m); q += __shfl_xor(q, m); }
                    float mu = s * (1.f/128.f);
                    float rs = rsqrtf(q * (1.f/128.f) - mu*mu + 1e-5f);
                    float4 g = *(const float4*)(sLG + c);
                    float4 b = *(const float4*)(sLBt + c);
                    float n0 = (v.x-mu)*rs*g.x + b.x, n1 = (v.y-mu)*rs*g.y + b.y;
                    float n2 = (v.z-mu)*rs*g.z + b.z, n3 = (v.w-mu)*rs*g.w + b.w;
                    uint_t h0 = f2bf(n0), h1 = f2bf(n1), h2 = f2bf(n2), h3 = f2bf(n3);
                    uint2 ph; ph.x = h0 | (h1 << 16); ph.y = h2 | (h3 << 16);
                    uint_t e0 = f2bf(n0 - bf2f(h0)), e1 = f2bf(n1 - bf2f(h1));
                    uint_t e2 = f2bf(n2 - bf2f(h2)), e3 = f2bf(n3 - bf2f(h3));
                    uint2 pl; pl.x = e0 | (e1 << 16); pl.y = e2 | (e3 << 16);
                    *(uint2*)(sXh + r*XBS + c) = ph;
                    *(uint2*)(sXl + r*XBS + c) = pl;
                    float4 a = *(const float4*)(sAW + c);
                    float sp = n0*a.x + n1*a.y + n2*a.z + n3*a.w;
                    #pragma unroll
                    for (int m = 1; m <= 16; m <<= 1) sp += __shfl_xor(sp, m);
                    if ((t & 31) == 0) sK[r] = 1.f / (1.f + expf(-(sp + abv)));
                }
            }
        }
        __syncthreads();

        // ---- (b) MFMA GEMM: A = W-strip from L2, B = xn rows 0..15, C = broadcast row 16 ----
        {
            short8 Bh[4], Bl[4], Ch[4], Cl[4];
            #pragma unroll
            for (int ks = 0; ks < 4; ks++){
                Bh[ks] = *(const short8*)(sXh + l16*XBS + quad*8 + ks*32);
                Bl[ks] = *(const short8*)(sXl + l16*XBS + quad*8 + ks*32);
                Ch[ks] = *(const short8*)(sXh + 16*XBS + quad*8 + ks*32);
                Cl[ks] = *(const short8*)(sXl + 16*XBS + quad*8 + ks*32);
            }
            const int fbase = wave * 160;
            #pragma unroll 2
            for (int ft = 0; ft < 10; ft++){
                int f0 = fbase + ft*16;
                const ushort_t* ah = whi + (f0 + l16)*128 + quad*8;
                const ushort_t* al = wlo + (f0 + l16)*128 + quad*8;
                short8 Ah[4], Al[4];
                #pragma unroll
                for (int ks = 0; ks < 4; ks++){
                    Ah[ks] = *(const short8*)(ah + ks*32);
                    Al[ks] = *(const short8*)(al + ks*32);
                }
                float4 bb = *(const float4*)(sBC + f0 + quad*4);
                f32x4 acc, ac2;
                acc[0] = bb.x; acc[1] = bb.y; acc[2] = bb.z; acc[3] = bb.w;
                ac2 = acc;
                #pragma unroll
                for (int ks = 0; ks < 4; ks++){
                    acc = __builtin_amdgcn_mfma_f32_16x16x32_bf16(Ah[ks], Bh[ks], acc, 0, 0, 0);
                    ac2 = __builtin_amdgcn_mfma_f32_16x16x32_bf16(Ah[ks], Ch[ks], ac2, 0, 0, 0);
                    acc = __builtin_amdgcn_mfma_f32_16x16x32_bf16(Ah[ks], Bl[ks], acc, 0, 0, 0);
                    ac2 = __builtin_amdgcn_mfma_f32_16x16x32_bf16(Ah[ks], Cl[ks], ac2, 0, 0, 0);
                    acc = __builtin_amdgcn_mfma_f32_16x16x32_bf16(Al[ks], Bh[ks], acc, 0, 0, 0);
                    ac2 = __builtin_amdgcn_mfma_f32_16x16x32_bf16(Al[ks], Ch[ks], ac2, 0, 0, 0);
                }
                int fb = f0 + quad*4;
                if (f0 < 512){
                    ushort_t* dst0 = (f0 < 256) ? (sLb + l16*LBS + fb) : (sRb + l16*LBS + (fb-256));
                    uint2 pk;
                    pk.x = f2bf(acc[0]) | (f2bf(acc[1]) << 16);
                    pk.y = f2bf(acc[2]) | (f2bf(acc[3]) << 16);
                    *(uint2*)dst0 = pk;
                    if (l16 == 0){
                        ushort_t* dst1 = (f0 < 256) ? (sLb + 16*LBS + fb) : (sRb + 16*LBS + (fb-256));
                        uint2 p2;
                        p2.x = f2bf(ac2[0]) | (f2bf(ac2[1]) << 16);
                        p2.y = f2bf(ac2[2]) | (f2bf(ac2[3]) << 16);
                        *(uint2*)dst1 = p2;
                    }
                } else {
                    float4 o; o.x = acc[0]; o.y = acc[1]; o.z = acc[2]; o.w = acc[3];
                    *(float4*)(sV + l16*XS + (fb-512)) = o;
                    if (l16 == 0){
                        float4 o2; o2.x = ac2[0]; o2.y = ac2[1]; o2.z = ac2[2]; o2.w = ac2[3];
                        *(float4*)(sV + 16*XS + (fb-512)) = o2;
                    }
                }
            }
        }
        __syncthreads();

        // ---- (c) attention scores: dense 49-pair list x 2 heads (sS aliases dead sXh) ----
        if (t < 98){
            int h = (t >= 49);
            int p = t - 49*h;
            unsigned short pr = PAIR[p];
            int i = pr >> 8, j = pr & 255;
            const uint4* lp = (const uint4*)(sLb + i*LBS + h*128);
            const uint4* rp = (const uint4*)(sRb + j*LBS + h*128);
            float acc = 0.f;
            #pragma unroll
            for (int d = 0; d < 16; d++){
                uint4 lu = lp[d], ru = rp[d];
                float4 p0 = *(const float4*)(sPW + d*8);
                float4 p1 = *(const float4*)(sPW + d*8 + 4);
                acc += lrelu02(bflo(lu.x) + bflo(ru.x)) * p0.x;
                acc += lrelu02(bfhi(lu.x) + bfhi(ru.x)) * p0.y;
                acc += lrelu02(bflo(lu.y) + bflo(ru.y)) * p0.z;
                acc += lrelu02(bfhi(lu.y) + bfhi(ru.y)) * p0.w;
                acc += lrelu02(bflo(lu.z) + bflo(ru.z)) * p1.x;
                acc += lrelu02(bfhi(lu.z) + bfhi(ru.z)) * p1.y;
                acc += lrelu02(bflo(lu.w) + bflo(ru.w)) * p1.z;
                acc += lrelu02(bfhi(lu.w) + bfhi(ru.w)) * p1.w;
            }
            sS[(h*NJ + i)*SS + j] = acc + sBC[640];
        }
        __syncthreads();

        // ---- (d) masked softmax (t<34) ----
        if (t < 34){
            int h = (t >= NJ);
            int i = t - h*NJ;
            float* sp = sS + (h*NJ + i)*SS;
            unsigned int m = ADJM[i];
            float mx = -1e30f;
            #pragma unroll
            for (int j = 0; j < NJ; j++) if ((m >> j) & 1u) mx = fmaxf(mx, sp[j]);
            float pv[NJ]; float sum = 0.f;
            #pragma unroll
            for (int j = 0; j < NJ; j++){
                if ((m >> j) & 1u){ pv[j] = expf(sp[j] - mx); sum += pv[j]; }
                else pv[j] = 0.f;
            }
            float inv = 1.f / sum;
            #pragma unroll
            for (int j = 0; j < NJ; j++) sp[j] = pv[j]*inv;
        }
        __syncthreads();

        // ---- (e) PV + gelu + blend (x0 in regs) -> new x in sX ----
        #pragma unroll
        for (int p = 0; p < 3; p++){
            int idx = t + (p << 8);
            if (p < 2 || t < 32){
                int r = idx >> 5, cg = idx & 31;
                int c = cg << 2, h = cg >> 4;
                const float* sp = sS + (h*NJ + r)*SS;
                float a0 = 0.f, a1 = 0.f, a2 = 0.f, a3 = 0.f;
                #pragma unroll
                for (int j = 0; j < NJ; j++){
                    float pj = sp[j];
                    float4 vv = *(const float4*)(sV + j*XS + c);
                    a0 += pj*vv.x; a1 += pj*vv.y; a2 += pj*vv.z; a3 += pj*vv.w;
                }
                a0 = gelu_exact(a0); a1 = gelu_exact(a1); a2 = gelu_exact(a2); a3 = gelu_exact(a3);
                float sk = sK[r];
                float4 x0v = x0r[p];
                float4 nx;
                nx.x = (1.f-sk)*a0 + sk*x0v.x;  nx.y = (1.f-sk)*a1 + sk*x0v.y;
                nx.z = (1.f-sk)*a2 + sk*x0v.z;  nx.w = (1.f-sk)*a3 + sk*x0v.w;
                *(float4*)(sX + r*XS + c) = nx;
            }
        }
        __syncthreads();
    }

    // ---- store ----
    for (int idx = t; idx < 544; idx += 256)
        *(float4*)(out + base + idx*4) = *(const float4*)(sX + (idx>>5)*XS + ((idx&31)<<2));
}

extern "C" void kernel_launch(void* const* d_in, const int* in_sizes, int n_in,
                              void* d_out, int out_size, void* d_ws, size_t ws_size,
                              hipStream_t stream) {
    const float* x   = (const float*)d_in[0];
    const float* og  = (const float*)d_in[1];
    const float* ob  = (const float*)d_in[2];
    const float* lg  = (const float*)d_in[3];
    const float* lb  = (const float*)d_in[4];
    const float* aw  = (const float*)d_in[5];
    const float* ab  = (const float*)d_in[6];
    const float* w1  = (const float*)d_in[7];
    const float* b1  = (const float*)d_in[8];
    const float* w2  = (const float*)d_in[9];
    const float* b2  = (const float*)d_in[10];
    const float* psw = (const float*)d_in[11];
    const float* psb = (const float*)d_in[12];
    const float* vw  = (const float*)d_in[13];
    const float* vb  = (const float*)d_in[14];
    float* out = (float*)d_out;

    // workspace: whi (640*128 bf16) + wlo (640*128 bf16) + bcat (640 f32) = 330,240 B
    ushort_t* whi = (ushort_t*)d_ws;
    ushort_t* wlo = whi + 640*128;
    float* bcat = (float*)(wlo + 640*128);

    prep_kernel<<<dim3(320), dim3(256), 0, stream>>>(w1, b1, w2, b2, vw, vb, whi, wlo, bcat);

    int BT = in_sizes[0] / TOKE;   // 3888 tokens
    appnp_kernel<<<dim3(BT), dim3(256), 0, stream>>>(
        x, og, ob, lg, lb, aw, ab, psw, psb, whi, wlo, bcat, out);
}